// Round 1
// baseline (1953.703 us; speedup 1.0000x reference)
//
#include <hip/hip_runtime.h>
#include <math.h>

// Problem constants (fixed by reference)
#define D_EMBEDC 1024
#define N_HEADSC 16
#define D_HEADC  64
#define BATCHC   2
#define S1C      2048
#define S2C      2048

// ---------------------------------------------------------------------------
// GEMM-NT: C[m,n] = sum_k A[m,k] * W[n,k] + bias[n]
// A: [M,K] row-major, W: [N,K] row-major (torch Linear weight), both k-contig.
// EPILOGUE 0: out row-major [M,N]
// EPILOGUE 1: out head-split [B, H, S, 64] where m=(b,s), n=(h,d)
// Tiles: 64x64, BK=16; 256 threads, 4x4 per thread.
// ---------------------------------------------------------------------------
template<int EPILOGUE>
__global__ __launch_bounds__(256)
void gemm_nt(const float* __restrict__ A, const float* __restrict__ W,
             const float* __restrict__ bias, float* __restrict__ out,
             int M, int N, int K, int S)
{
    const int BM = 64, BN = 64, BK = 16;
    __shared__ float As[BK][BM + 1];
    __shared__ float Bs[BK][BN + 1];

    const int tid = threadIdx.x;
    const int m0 = blockIdx.x * BM;
    const int n0 = blockIdx.y * BN;
    const int tx = tid % 16, ty = tid / 16;
    const int lk = tid % BK;   // 0..15 (k within tile)
    const int lr = tid / BK;   // 0..15 (row group)

    float acc[4][4] = {};

    for (int k0 = 0; k0 < K; k0 += BK) {
#pragma unroll
        for (int i = 0; i < 4; ++i) {
            As[lk][lr + 16 * i] = A[(size_t)(m0 + lr + 16 * i) * K + k0 + lk];
            Bs[lk][lr + 16 * i] = W[(size_t)(n0 + lr + 16 * i) * K + k0 + lk];
        }
        __syncthreads();
#pragma unroll
        for (int kk = 0; kk < BK; ++kk) {
            float a[4], b[4];
#pragma unroll
            for (int i = 0; i < 4; ++i) a[i] = As[kk][ty * 4 + i];
#pragma unroll
            for (int j = 0; j < 4; ++j) b[j] = Bs[kk][tx * 4 + j];
#pragma unroll
            for (int i = 0; i < 4; ++i)
#pragma unroll
                for (int j = 0; j < 4; ++j)
                    acc[i][j] += a[i] * b[j];
        }
        __syncthreads();
    }

#pragma unroll
    for (int i = 0; i < 4; ++i) {
        const int m = m0 + ty * 4 + i;
        const int n = n0 + tx * 4;           // 4 consecutive n per thread
        float4 v;
        v.x = acc[i][0] + bias[n + 0];
        v.y = acc[i][1] + bias[n + 1];
        v.z = acc[i][2] + bias[n + 2];
        v.w = acc[i][3] + bias[n + 3];
        if (EPILOGUE == 0) {
            *reinterpret_cast<float4*>(&out[(size_t)m * N + n]) = v;
        } else {
            const int b = m / S, s = m % S;
            const int h = n / D_HEADC, d = n % D_HEADC;  // 4-group never crosses a head (n0%64==0)
            float* dst = &out[((((size_t)b * N_HEADSC + h) * S + s) * D_HEADC) + d];
            *reinterpret_cast<float4*>(dst) = v;
        }
    }
}

// ---------------------------------------------------------------------------
// Scores: P[z, q, k] = (1/8) * dot(Q[z,q,:], K[z,k,:])   (z = b*H + h)
// Q,K: [Z, S, 64]. Tiled NT GEMM, K-dim = 64.
// ---------------------------------------------------------------------------
__global__ __launch_bounds__(256)
void scores_kernel(const float* __restrict__ Q, const float* __restrict__ Km,
                   float* __restrict__ P)
{
    const int BM = 64, BN = 64, BK = 16;
    __shared__ float As[BK][BM + 1];
    __shared__ float Bs[BK][BN + 1];

    const int z = blockIdx.z;
    const float* A = Q  + (size_t)z * S1C * D_HEADC;
    const float* W = Km + (size_t)z * S2C * D_HEADC;
    float* out = P + (size_t)z * S1C * S2C;

    const int tid = threadIdx.x;
    const int m0 = blockIdx.x * BM;
    const int n0 = blockIdx.y * BN;
    const int tx = tid % 16, ty = tid / 16;
    const int lk = tid % BK;
    const int lr = tid / BK;

    float acc[4][4] = {};

    for (int k0 = 0; k0 < D_HEADC; k0 += BK) {
#pragma unroll
        for (int i = 0; i < 4; ++i) {
            As[lk][lr + 16 * i] = A[(size_t)(m0 + lr + 16 * i) * D_HEADC + k0 + lk];
            Bs[lk][lr + 16 * i] = W[(size_t)(n0 + lr + 16 * i) * D_HEADC + k0 + lk];
        }
        __syncthreads();
#pragma unroll
        for (int kk = 0; kk < BK; ++kk) {
            float a[4], b[4];
#pragma unroll
            for (int i = 0; i < 4; ++i) a[i] = As[kk][ty * 4 + i];
#pragma unroll
            for (int j = 0; j < 4; ++j) b[j] = Bs[kk][tx * 4 + j];
#pragma unroll
            for (int i = 0; i < 4; ++i)
#pragma unroll
                for (int j = 0; j < 4; ++j)
                    acc[i][j] += a[i] * b[j];
        }
        __syncthreads();
    }

    const float scale = 0.125f;  // 1/sqrt(64)
#pragma unroll
    for (int i = 0; i < 4; ++i) {
        const int m = m0 + ty * 4 + i;
        const int n = n0 + tx * 4;
        float4 v;
        v.x = acc[i][0] * scale;
        v.y = acc[i][1] * scale;
        v.z = acc[i][2] * scale;
        v.w = acc[i][3] * scale;
        *reinterpret_cast<float4*>(&out[(size_t)m * S2C + n]) = v;
    }
}

// ---------------------------------------------------------------------------
// Row softmax in place over rows of length 2048. One block (256 thr) per row.
// ---------------------------------------------------------------------------
__global__ __launch_bounds__(256)
void softmax_kernel(float* __restrict__ P)
{
    const size_t row = blockIdx.x;
    float* p = P + row * (size_t)S2C;
    const int tid = threadIdx.x;

    float4 v0 = reinterpret_cast<float4*>(p)[tid];
    float4 v1 = reinterpret_cast<float4*>(p)[tid + 256];

    float m = fmaxf(fmaxf(fmaxf(v0.x, v0.y), fmaxf(v0.z, v0.w)),
                    fmaxf(fmaxf(v1.x, v1.y), fmaxf(v1.z, v1.w)));
#pragma unroll
    for (int off = 32; off > 0; off >>= 1) m = fmaxf(m, __shfl_down(m, off));

    __shared__ float red[8];
    if ((tid & 63) == 0) red[tid >> 6] = m;
    __syncthreads();
    m = fmaxf(fmaxf(red[0], red[1]), fmaxf(red[2], red[3]));

    v0.x = __expf(v0.x - m); v0.y = __expf(v0.y - m);
    v0.z = __expf(v0.z - m); v0.w = __expf(v0.w - m);
    v1.x = __expf(v1.x - m); v1.y = __expf(v1.y - m);
    v1.z = __expf(v1.z - m); v1.w = __expf(v1.w - m);

    float s = v0.x + v0.y + v0.z + v0.w + v1.x + v1.y + v1.z + v1.w;
#pragma unroll
    for (int off = 32; off > 0; off >>= 1) s += __shfl_down(s, off);
    if ((tid & 63) == 0) red[4 + (tid >> 6)] = s;
    __syncthreads();
    const float inv = 1.0f / (red[4] + red[5] + red[6] + red[7]);

    v0.x *= inv; v0.y *= inv; v0.z *= inv; v0.w *= inv;
    v1.x *= inv; v1.y *= inv; v1.z *= inv; v1.w *= inv;
    reinterpret_cast<float4*>(p)[tid] = v0;
    reinterpret_cast<float4*>(p)[tid + 256] = v1;
}

// ---------------------------------------------------------------------------
// PV: attn_out[b, q, h*64+d] = sum_k P[z,q,k] * V[z,k,d]   (GEMM-NN, N=64)
// ---------------------------------------------------------------------------
__global__ __launch_bounds__(256)
void pv_kernel(const float* __restrict__ P, const float* __restrict__ V,
               float* __restrict__ out)
{
    const int BM = 64, BN = 64, BK = 16;
    __shared__ float As[BK][BM + 1];
    __shared__ float Bs[BK][BN];

    const int z = blockIdx.z;
    const int b = z / N_HEADSC, h = z % N_HEADSC;
    const float* A  = P + (size_t)z * S1C * S2C;
    const float* Bv = V + (size_t)z * S2C * D_HEADC;

    const int tid = threadIdx.x;
    const int m0 = blockIdx.x * BM;
    const int tx = tid % 16, ty = tid / 16;
    const int lk = tid % BK;   // A-load k
    const int lr = tid / BK;   // A-load row group
    const int bn = tid % BN;   // B-load col
    const int bk = tid / BN;   // B-load k group (0..3)

    float acc[4][4] = {};

    for (int k0 = 0; k0 < S2C; k0 += BK) {
#pragma unroll
        for (int i = 0; i < 4; ++i)
            As[lk][lr + 16 * i] = A[(size_t)(m0 + lr + 16 * i) * S2C + k0 + lk];
#pragma unroll
        for (int i = 0; i < 4; ++i)
            Bs[bk + 4 * i][bn] = Bv[(size_t)(k0 + bk + 4 * i) * D_HEADC + bn];
        __syncthreads();
#pragma unroll
        for (int kk = 0; kk < BK; ++kk) {
            float a[4], bb[4];
#pragma unroll
            for (int i = 0; i < 4; ++i) a[i] = As[kk][ty * 4 + i];
#pragma unroll
            for (int j = 0; j < 4; ++j) bb[j] = Bs[kk][tx * 4 + j];
#pragma unroll
            for (int i = 0; i < 4; ++i)
#pragma unroll
                for (int j = 0; j < 4; ++j)
                    acc[i][j] += a[i] * bb[j];
        }
        __syncthreads();
    }

#pragma unroll
    for (int i = 0; i < 4; ++i) {
        const int q = m0 + ty * 4 + i;
        const int d = tx * 4;
        float4 v;
        v.x = acc[i][0]; v.y = acc[i][1]; v.z = acc[i][2]; v.w = acc[i][3];
        float* dst = &out[((size_t)b * S1C + q) * D_EMBEDC + h * D_HEADC + d];
        *reinterpret_cast<float4*>(dst) = v;
    }
}

// ---------------------------------------------------------------------------
// Launch
// ---------------------------------------------------------------------------
extern "C" void kernel_launch(void* const* d_in, const int* in_sizes, int n_in,
                              void* d_out, int out_size, void* d_ws, size_t ws_size,
                              hipStream_t stream)
{
    const float* x1 = (const float*)d_in[0];
    const float* x2 = (const float*)d_in[1];
    const float* Wq = (const float*)d_in[2];
    const float* bq = (const float*)d_in[3];
    const float* Wk = (const float*)d_in[4];
    const float* bk = (const float*)d_in[5];
    const float* Wv = (const float*)d_in[6];
    const float* bv = (const float*)d_in[7];
    const float* Wo = (const float*)d_in[8];
    const float* bo = (const float*)d_in[9];

    float* out   = (float*)d_out;                                  // [B,S1,D]
    float* attnw = out + (size_t)BATCHC * S1C * D_EMBEDC;          // [B,H,S1,S2]

    // Workspace layout (needs 64 MiB): Q, K, V in [B,H,S,64], attn_out [B,S1,D]
    const size_t headsz = (size_t)BATCHC * N_HEADSC * S1C * D_HEADC;  // 4.19M floats
    float* Qb = (float*)d_ws;
    float* Kb = Qb + headsz;
    float* Vb = Kb + headsz;
    float* Ab = Vb + headsz;

    const dim3 blk(256);
    const int M = BATCHC * S1C;  // 4096

    // Projections (head-split epilogue)
    gemm_nt<1><<<dim3(M / 64, D_EMBEDC / 64), blk, 0, stream>>>(x1, Wq, bq, Qb, M, D_EMBEDC, D_EMBEDC, S1C);
    gemm_nt<1><<<dim3(M / 64, D_EMBEDC / 64), blk, 0, stream>>>(x2, Wk, bk, Kb, M, D_EMBEDC, D_EMBEDC, S2C);
    gemm_nt<1><<<dim3(M / 64, D_EMBEDC / 64), blk, 0, stream>>>(x2, Wv, bv, Vb, M, D_EMBEDC, D_EMBEDC, S2C);

    // Scores (scaled) straight into attn_weights output region
    scores_kernel<<<dim3(S1C / 64, S2C / 64, BATCHC * N_HEADSC), blk, 0, stream>>>(Qb, Kb, attnw);

    // Softmax in place
    softmax_kernel<<<dim3(BATCHC * N_HEADSC * S1C), blk, 0, stream>>>(attnw);

    // attn_out = P @ V, re-interleaved to [B,S1,D]
    pv_kernel<<<dim3(S1C / 64, 1, BATCHC * N_HEADSC), blk, 0, stream>>>(attnw, Vb, Ab);

    // Output projection
    gemm_nt<0><<<dim3(M / 64, D_EMBEDC / 64), blk, 0, stream>>>(Ab, Wo, bo, out, M, D_EMBEDC, D_EMBEDC, S1C);
}

// Round 2
// 1027.705 us; speedup vs baseline: 1.9010x; 1.9010x over previous
//
#include <hip/hip_runtime.h>
#include <stdint.h>

#define D_EMBEDC 1024
#define N_HEADSC 16
#define D_HEADC  64
#define BATCHC   2
#define S1C      2048
#define S2C      2048

typedef __attribute__((ext_vector_type(8))) short short8;
typedef __attribute__((ext_vector_type(4))) float floatx4;

__device__ __forceinline__ ushort f2bf(float x) {
    uint32_t u = __float_as_uint(x);
    uint32_t r = (u + 0x7fffu + ((u >> 16) & 1u)) >> 16;  // RNE
    return (ushort)r;
}

__device__ __forceinline__ void glds16(const void* g, void* l) {
    __builtin_amdgcn_global_load_lds(
        (const __attribute__((address_space(1))) void*)g,
        (__attribute__((address_space(3))) void*)l, 16, 0, 0);
}

// ---------------------------------------------------------------------------
// fp32 -> bf16 cast, 4 elements/thread
// ---------------------------------------------------------------------------
__global__ __launch_bounds__(256)
void cast_f32_bf16(const float4* __restrict__ in, ushort4* __restrict__ out)
{
    const int i = blockIdx.x * 256 + threadIdx.x;
    float4 v = in[i];
    ushort4 o;
    o.x = f2bf(v.x); o.y = f2bf(v.y); o.z = f2bf(v.z); o.w = f2bf(v.w);
    out[i] = o;
}

// ---------------------------------------------------------------------------
// Fused QKV projection: 128x128 tile MFMA GEMM-NT over K=1024.
// z=0: Q = x1@Wq^T+bq -> Qb [z2][s][64] bf16
// z=1: K = x2@Wk^T+bk -> Kb [z2][s][64] bf16
// z=2: V = x2@Wv^T+bv -> Vtb [z2][d][s2] bf16 (transposed for PV B-operand)
// ---------------------------------------------------------------------------
__global__ __launch_bounds__(256)
void qkv_mfma(const ushort* __restrict__ x1b, const ushort* __restrict__ x2b,
              const ushort* __restrict__ Wqb, const ushort* __restrict__ Wkb,
              const ushort* __restrict__ Wvb,
              const float* __restrict__ bq, const float* __restrict__ bk,
              const float* __restrict__ bv,
              ushort* __restrict__ Qb, ushort* __restrict__ Kb,
              ushort* __restrict__ Vtb)
{
    __shared__ __align__(16) ushort As[128 * 32];
    __shared__ __align__(16) ushort Bs[128 * 32];

    const int which = blockIdx.z;
    const ushort* A = (which == 0) ? x1b : x2b;
    const ushort* W = (which == 0) ? Wqb : (which == 1) ? Wkb : Wvb;
    const float* bias = (which == 0) ? bq : (which == 1) ? bk : bv;

    const int tid = threadIdx.x;
    const int lane = tid & 63;
    const int wave = tid >> 6;
    const int m0 = blockIdx.x * 128;
    const int n0 = blockIdx.y * 128;
    const int wm = (wave & 1) * 64;
    const int wn = (wave >> 1) * 64;
    const int K = 1024;

    floatx4 zero = {0.f, 0.f, 0.f, 0.f};
    floatx4 acc[4][4];
#pragma unroll
    for (int i = 0; i < 4; ++i)
#pragma unroll
        for (int j = 0; j < 4; ++j) acc[i][j] = zero;

    for (int k0 = 0; k0 < K; k0 += 32) {
#pragma unroll
        for (int i = 0; i < 2; ++i) {
            const int f = i * 256 + tid;
            const int r = f >> 2, kc = (f & 3) * 8;
            glds16(A + (size_t)(m0 + r) * K + k0 + kc, &As[f * 8]);
            glds16(W + (size_t)(n0 + r) * K + k0 + kc, &Bs[f * 8]);
        }
        __syncthreads();
        short8 a[4], b[4];
#pragma unroll
        for (int t = 0; t < 4; ++t) {
            a[t] = *(const short8*)&As[(wm + t * 16 + (lane & 15)) * 32 + (lane >> 4) * 8];
            b[t] = *(const short8*)&Bs[(wn + t * 16 + (lane & 15)) * 32 + (lane >> 4) * 8];
        }
#pragma unroll
        for (int im = 0; im < 4; ++im)
#pragma unroll
            for (int in = 0; in < 4; ++in)
                acc[im][in] = __builtin_amdgcn_mfma_f32_16x16x32_bf16(a[im], b[in], acc[im][in], 0, 0, 0);
        __syncthreads();
    }

    // C/D layout: row(m) = (lane>>4)*4 + reg, col(n) = lane&15
#pragma unroll
    for (int im = 0; im < 4; ++im) {
#pragma unroll
        for (int in = 0; in < 4; ++in) {
            const int mbase = m0 + wm + im * 16 + ((lane >> 4) << 2);
            const int n = n0 + wn + in * 16 + (lane & 15);
            const int h = n >> 6, d = n & 63;
            const float bv_ = bias[n];
            if (which < 2) {
                ushort* outp = (which == 0) ? Qb : Kb;
#pragma unroll
                for (int r = 0; r < 4; ++r) {
                    const int m = mbase + r;
                    const int bb = m >> 11, s = m & 2047;
                    outp[((((size_t)(bb * 16 + h)) * 2048 + s) << 6) + d] =
                        f2bf(acc[im][in][r] + bv_);
                }
            } else {
                const int m = mbase;
                const int bb = m >> 11, s = m & 2047;
                const size_t base = (((size_t)(bb * 16 + h) * 64 + d) << 11) + s;
                ushort4 pk;
                pk.x = f2bf(acc[im][in][0] + bv_);
                pk.y = f2bf(acc[im][in][1] + bv_);
                pk.z = f2bf(acc[im][in][2] + bv_);
                pk.w = f2bf(acc[im][in][3] + bv_);
                *(ushort4*)&Vtb[base] = pk;
            }
        }
    }
}

// ---------------------------------------------------------------------------
// Scores: P[z,q,s2] = 0.125 * Q[z,q,:].K[z,s2,:]  (K-dim = 64), fp32 out
// ---------------------------------------------------------------------------
__global__ __launch_bounds__(256)
void scores_mfma(const ushort* __restrict__ Qb, const ushort* __restrict__ Kb,
                 float* __restrict__ P)
{
    __shared__ __align__(16) ushort As[128 * 32];
    __shared__ __align__(16) ushort Bs[128 * 32];

    const int z = blockIdx.z;
    const ushort* A = Qb + (size_t)z * S1C * D_HEADC;
    const ushort* W = Kb + (size_t)z * S2C * D_HEADC;
    float* out = P + (size_t)z * S1C * S2C;

    const int tid = threadIdx.x;
    const int lane = tid & 63;
    const int wave = tid >> 6;
    const int m0 = blockIdx.x * 128;
    const int n0 = blockIdx.y * 128;
    const int wm = (wave & 1) * 64;
    const int wn = (wave >> 1) * 64;

    floatx4 zero = {0.f, 0.f, 0.f, 0.f};
    floatx4 acc[4][4];
#pragma unroll
    for (int i = 0; i < 4; ++i)
#pragma unroll
        for (int j = 0; j < 4; ++j) acc[i][j] = zero;

    for (int k0 = 0; k0 < D_HEADC; k0 += 32) {
#pragma unroll
        for (int i = 0; i < 2; ++i) {
            const int f = i * 256 + tid;
            const int r = f >> 2, kc = (f & 3) * 8;
            glds16(A + (size_t)(m0 + r) * D_HEADC + k0 + kc, &As[f * 8]);
            glds16(W + (size_t)(n0 + r) * D_HEADC + k0 + kc, &Bs[f * 8]);
        }
        __syncthreads();
        short8 a[4], b[4];
#pragma unroll
        for (int t = 0; t < 4; ++t) {
            a[t] = *(const short8*)&As[(wm + t * 16 + (lane & 15)) * 32 + (lane >> 4) * 8];
            b[t] = *(const short8*)&Bs[(wn + t * 16 + (lane & 15)) * 32 + (lane >> 4) * 8];
        }
#pragma unroll
        for (int im = 0; im < 4; ++im)
#pragma unroll
            for (int in = 0; in < 4; ++in)
                acc[im][in] = __builtin_amdgcn_mfma_f32_16x16x32_bf16(a[im], b[in], acc[im][in], 0, 0, 0);
        __syncthreads();
    }

#pragma unroll
    for (int im = 0; im < 4; ++im)
#pragma unroll
        for (int in = 0; in < 4; ++in) {
            const int mbase = m0 + wm + im * 16 + ((lane >> 4) << 2);
            const int n = n0 + wn + in * 16 + (lane & 15);
#pragma unroll
            for (int r = 0; r < 4; ++r)
                out[(size_t)(mbase + r) * S2C + n] = acc[im][in][r] * 0.125f;
        }
}

// ---------------------------------------------------------------------------
// Row softmax in place (rows of 2048), one 256-thread block per row
// ---------------------------------------------------------------------------
__global__ __launch_bounds__(256)
void softmax_kernel(float* __restrict__ P)
{
    const size_t row = blockIdx.x;
    float* p = P + row * (size_t)S2C;
    const int tid = threadIdx.x;

    float4 v0 = reinterpret_cast<float4*>(p)[tid];
    float4 v1 = reinterpret_cast<float4*>(p)[tid + 256];

    float m = fmaxf(fmaxf(fmaxf(v0.x, v0.y), fmaxf(v0.z, v0.w)),
                    fmaxf(fmaxf(v1.x, v1.y), fmaxf(v1.z, v1.w)));
#pragma unroll
    for (int off = 32; off > 0; off >>= 1) m = fmaxf(m, __shfl_down(m, off));

    __shared__ float red[8];
    if ((tid & 63) == 0) red[tid >> 6] = m;
    __syncthreads();
    m = fmaxf(fmaxf(red[0], red[1]), fmaxf(red[2], red[3]));

    v0.x = __expf(v0.x - m); v0.y = __expf(v0.y - m);
    v0.z = __expf(v0.z - m); v0.w = __expf(v0.w - m);
    v1.x = __expf(v1.x - m); v1.y = __expf(v1.y - m);
    v1.z = __expf(v1.z - m); v1.w = __expf(v1.w - m);

    float s = v0.x + v0.y + v0.z + v0.w + v1.x + v1.y + v1.z + v1.w;
#pragma unroll
    for (int off = 32; off > 0; off >>= 1) s += __shfl_down(s, off);
    if ((tid & 63) == 0) red[4 + (tid >> 6)] = s;
    __syncthreads();
    const float inv = 1.0f / (red[4] + red[5] + red[6] + red[7]);

    v0.x *= inv; v0.y *= inv; v0.z *= inv; v0.w *= inv;
    v1.x *= inv; v1.y *= inv; v1.z *= inv; v1.w *= inv;
    reinterpret_cast<float4*>(p)[tid] = v0;
    reinterpret_cast<float4*>(p)[tid + 256] = v1;
}

// ---------------------------------------------------------------------------
// PV: attn_out[b, q, h*64+d] = sum_k P[z,q,k] * Vt[z,d,k]   (bf16 out)
// A = fp32 P (cast during LDS staging), B = bf16 Vt via global_load_lds.
// Tile 128(m) x 64(n), BK=32; 4 waves, each 32(m) x 64(n).
// ---------------------------------------------------------------------------
__global__ __launch_bounds__(256)
void pv_mfma(const float* __restrict__ P, const ushort* __restrict__ Vtb,
             ushort* __restrict__ Ab)
{
    __shared__ __align__(16) ushort As[128 * 32];
    __shared__ __align__(16) ushort Bs[64 * 32];

    const int z = blockIdx.z;
    const float* Pz = P + (size_t)z * S1C * S2C;
    const ushort* Vt = Vtb + (size_t)z * D_HEADC * S2C;

    const int tid = threadIdx.x;
    const int lane = tid & 63;
    const int wave = tid >> 6;
    const int m0 = blockIdx.x * 128;
    const int wm = wave * 32;

    floatx4 zero = {0.f, 0.f, 0.f, 0.f};
    floatx4 acc[2][4];
#pragma unroll
    for (int i = 0; i < 2; ++i)
#pragma unroll
        for (int j = 0; j < 4; ++j) acc[i][j] = zero;

    const int ar = tid >> 1, akh = (tid & 1) * 16;  // A staging: 16 fp32/thread

    for (int k0 = 0; k0 < S2C; k0 += 32) {
        // stage B (bf16, direct to LDS)
        glds16(Vt + (size_t)(tid >> 2) * S2C + k0 + (tid & 3) * 8, &Bs[tid * 8]);
        // stage A: fp32 -> bf16 cast
        {
            const float4* src = (const float4*)(Pz + (size_t)(m0 + ar) * S2C + k0 + akh);
            float4 v0 = src[0], v1 = src[1], v2 = src[2], v3 = src[3];
            ushort tmp[16];
            tmp[0] = f2bf(v0.x); tmp[1] = f2bf(v0.y); tmp[2] = f2bf(v0.z); tmp[3] = f2bf(v0.w);
            tmp[4] = f2bf(v1.x); tmp[5] = f2bf(v1.y); tmp[6] = f2bf(v1.z); tmp[7] = f2bf(v1.w);
            tmp[8] = f2bf(v2.x); tmp[9] = f2bf(v2.y); tmp[10] = f2bf(v2.z); tmp[11] = f2bf(v2.w);
            tmp[12] = f2bf(v3.x); tmp[13] = f2bf(v3.y); tmp[14] = f2bf(v3.z); tmp[15] = f2bf(v3.w);
            *(uint4*)&As[ar * 32 + akh] = *(uint4*)&tmp[0];
            *(uint4*)&As[ar * 32 + akh + 8] = *(uint4*)&tmp[8];
        }
        __syncthreads();
        short8 a[2], b[4];
#pragma unroll
        for (int t = 0; t < 2; ++t)
            a[t] = *(const short8*)&As[(wm + t * 16 + (lane & 15)) * 32 + (lane >> 4) * 8];
#pragma unroll
        for (int t = 0; t < 4; ++t)
            b[t] = *(const short8*)&Bs[(t * 16 + (lane & 15)) * 32 + (lane >> 4) * 8];
#pragma unroll
        for (int im = 0; im < 2; ++im)
#pragma unroll
            for (int in = 0; in < 4; ++in)
                acc[im][in] = __builtin_amdgcn_mfma_f32_16x16x32_bf16(a[im], b[in], acc[im][in], 0, 0, 0);
        __syncthreads();
    }

    const int h = z & 15, bb = z >> 4;
#pragma unroll
    for (int im = 0; im < 2; ++im)
#pragma unroll
        for (int in = 0; in < 4; ++in) {
            const int mbase = m0 + wm + im * 16 + ((lane >> 4) << 2);
            const int n = in * 16 + (lane & 15);
            const int col = h * 64 + n;
#pragma unroll
            for (int r = 0; r < 4; ++r)
                Ab[(size_t)(bb * 2048 + mbase + r) * 1024 + col] = f2bf(acc[im][in][r]);
        }
}

// ---------------------------------------------------------------------------
// Output projection: out[m,n] = attn_out[m,:].Wo[n,:] + bo[n], fp32 out
// ---------------------------------------------------------------------------
__global__ __launch_bounds__(256)
void gemm_out_mfma(const ushort* __restrict__ A, const ushort* __restrict__ W,
                   const float* __restrict__ bias, float* __restrict__ out)
{
    __shared__ __align__(16) ushort As[128 * 32];
    __shared__ __align__(16) ushort Bs[128 * 32];

    const int tid = threadIdx.x;
    const int lane = tid & 63;
    const int wave = tid >> 6;
    const int m0 = blockIdx.x * 128;
    const int n0 = blockIdx.y * 128;
    const int wm = (wave & 1) * 64;
    const int wn = (wave >> 1) * 64;
    const int K = 1024, N = 1024;

    floatx4 zero = {0.f, 0.f, 0.f, 0.f};
    floatx4 acc[4][4];
#pragma unroll
    for (int i = 0; i < 4; ++i)
#pragma unroll
        for (int j = 0; j < 4; ++j) acc[i][j] = zero;

    for (int k0 = 0; k0 < K; k0 += 32) {
#pragma unroll
        for (int i = 0; i < 2; ++i) {
            const int f = i * 256 + tid;
            const int r = f >> 2, kc = (f & 3) * 8;
            glds16(A + (size_t)(m0 + r) * K + k0 + kc, &As[f * 8]);
            glds16(W + (size_t)(n0 + r) * K + k0 + kc, &Bs[f * 8]);
        }
        __syncthreads();
        short8 a[4], b[4];
#pragma unroll
        for (int t = 0; t < 4; ++t) {
            a[t] = *(const short8*)&As[(wm + t * 16 + (lane & 15)) * 32 + (lane >> 4) * 8];
            b[t] = *(const short8*)&Bs[(wn + t * 16 + (lane & 15)) * 32 + (lane >> 4) * 8];
        }
#pragma unroll
        for (int im = 0; im < 4; ++im)
#pragma unroll
            for (int in = 0; in < 4; ++in)
                acc[im][in] = __builtin_amdgcn_mfma_f32_16x16x32_bf16(a[im], b[in], acc[im][in], 0, 0, 0);
        __syncthreads();
    }

#pragma unroll
    for (int im = 0; im < 4; ++im)
#pragma unroll
        for (int in = 0; in < 4; ++in) {
            const int mbase = m0 + wm + im * 16 + ((lane >> 4) << 2);
            const int n = n0 + wn + in * 16 + (lane & 15);
            const float bv_ = bias[n];
#pragma unroll
            for (int r = 0; r < 4; ++r)
                out[(size_t)(mbase + r) * N + n] = acc[im][in][r] + bv_;
        }
}

// ---------------------------------------------------------------------------
// Launch
// ---------------------------------------------------------------------------
extern "C" void kernel_launch(void* const* d_in, const int* in_sizes, int n_in,
                              void* d_out, int out_size, void* d_ws, size_t ws_size,
                              hipStream_t stream)
{
    const float* x1 = (const float*)d_in[0];
    const float* x2 = (const float*)d_in[1];
    const float* Wq = (const float*)d_in[2];
    const float* bq = (const float*)d_in[3];
    const float* Wk = (const float*)d_in[4];
    const float* bk = (const float*)d_in[5];
    const float* Wv = (const float*)d_in[6];
    const float* bv = (const float*)d_in[7];
    const float* Wo = (const float*)d_in[8];
    const float* bo = (const float*)d_in[9];

    float* out   = (float*)d_out;                          // [B,S1,D]
    float* attnw = out + (size_t)BATCHC * S1C * D_EMBEDC;  // [B,H,S1,S2]

    // bf16 workspace layout (~59 MB)
    const size_t XSZ = (size_t)BATCHC * S1C * D_EMBEDC;    // 4,194,304
    const size_t WSZ = (size_t)D_EMBEDC * D_EMBEDC;        // 1,048,576
    ushort* w = (ushort*)d_ws;
    ushort* x1b = w;            w += XSZ;
    ushort* x2b = w;            w += XSZ;
    ushort* Wqb = w;            w += WSZ;
    ushort* Wkb = w;            w += WSZ;
    ushort* Wvb = w;            w += WSZ;
    ushort* Wob = w;            w += WSZ;
    ushort* Qb  = w;            w += XSZ;
    ushort* Kb  = w;            w += XSZ;
    ushort* Vtb = w;            w += XSZ;
    ushort* Ab  = w;            w += XSZ;

    const dim3 blk(256);

    // casts
    cast_f32_bf16<<<dim3(XSZ / 1024), blk, 0, stream>>>((const float4*)x1, (ushort4*)x1b);
    cast_f32_bf16<<<dim3(XSZ / 1024), blk, 0, stream>>>((const float4*)x2, (ushort4*)x2b);
    cast_f32_bf16<<<dim3(WSZ / 1024), blk, 0, stream>>>((const float4*)Wq, (ushort4*)Wqb);
    cast_f32_bf16<<<dim3(WSZ / 1024), blk, 0, stream>>>((const float4*)Wk, (ushort4*)Wkb);
    cast_f32_bf16<<<dim3(WSZ / 1024), blk, 0, stream>>>((const float4*)Wv, (ushort4*)Wvb);
    cast_f32_bf16<<<dim3(WSZ / 1024), blk, 0, stream>>>((const float4*)Wo, (ushort4*)Wob);

    // fused QKV projections (z: 0=Q, 1=K, 2=V-transposed)
    qkv_mfma<<<dim3(32, 8, 3), blk, 0, stream>>>(x1b, x2b, Wqb, Wkb, Wvb,
                                                 bq, bk, bv, Qb, Kb, Vtb);

    // scores (scaled) into attn_weights output region
    scores_mfma<<<dim3(16, 16, 32), blk, 0, stream>>>(Qb, Kb, attnw);

    // softmax in place
    softmax_kernel<<<dim3(BATCHC * N_HEADSC * S1C), blk, 0, stream>>>(attnw);

    // PV -> attn_out (bf16, [B*S1, 1024])
    pv_mfma<<<dim3(16, 1, 32), blk, 0, stream>>>(attnw, Vtb, Ab);

    // output projection
    gemm_out_mfma<<<dim3(32, 8), blk, 0, stream>>>(Ab, Wob, bo, out);
}